// Round 1
// baseline (1887.349 us; speedup 1.0000x reference)
//
#include <hip/hip_runtime.h>
#include <hip/hip_bf16.h>
#include <stdint.h>

// Problem constants
#define MDIM 8192L    // B*S
#define NDIM 14336L
#define KDIM 4096L
#define GS   128

typedef __attribute__((ext_vector_type(8))) short bf16x8;
typedef __attribute__((ext_vector_type(4))) float floatx4;
typedef __attribute__((ext_vector_type(8))) unsigned short ushort8v;

__device__ __forceinline__ unsigned short f2bf(float f) {
    __hip_bfloat16 h = __float2bfloat16(f);
    return *reinterpret_cast<unsigned short*>(&h);
}

// ---------------- Prepass 1: x fp32 -> bf16 (8 elems/thread) ----------------
__global__ __launch_bounds__(256) void convert_x_kernel(
    const float* __restrict__ x, unsigned short* __restrict__ xb) {
    long idx = (long)blockIdx.x * 256 + threadIdx.x;   // 8 elems each
    const float4* xv = reinterpret_cast<const float4*>(x);
    float4 a = xv[idx * 2];
    float4 b = xv[idx * 2 + 1];
    ushort8v o;
    o[0] = f2bf(a.x); o[1] = f2bf(a.y); o[2] = f2bf(a.z); o[3] = f2bf(a.w);
    o[4] = f2bf(b.x); o[5] = f2bf(b.y); o[6] = f2bf(b.z); o[7] = f2bf(b.w);
    *reinterpret_cast<ushort8v*>(xb + idx * 8) = o;
}

// ------------- Prepass 2: W int4 (8 nibbles/int32) -> bf16 with group scale -
__global__ __launch_bounds__(256) void dequant_w_kernel(
    const int* __restrict__ wq, const float* __restrict__ wscale,
    unsigned short* __restrict__ wb) {
    long idx = (long)blockIdx.x * 256 + threadIdx.x;   // one int32 word = 8 nibbles
    int w = wq[idx];
    long n  = idx >> 9;          // K/8 = 512 words per row
    int  wk = (int)(idx & 511);
    float s = wscale[(n << 5) | (wk >> 4)];   // K/GS = 32 groups per row; 16 words/group
    ushort8v o;
#pragma unroll
    for (int j = 0; j < 8; ++j) {
        int v = (w << (28 - 4 * j)) >> 28;   // signed nibble j
        o[j] = f2bf((float)v * s);
    }
    *reinterpret_cast<ushort8v*>(wb + idx * 8) = o;
}

// ---------------- Main GEMM: C[m,n] = sum_k X[m,k]*W[n,k], fused epilogue ---
// Tile: BM=128, BN=128, BK=64 elems (128 B/row). 256 threads = 4 waves,
// each wave computes a 64x64 quadrant via 4x4 grid of 16x16x32 bf16 MFMAs.
// LDS rows are stored with 16B-chunk XOR swizzle: LDS[r][c] = G[r][c ^ (r&7)]
// -> global_load_lds (wave-uniform base + lane*16) works AND ds_read_b128
//    fragment loads are bank-uniform.
__global__ __launch_bounds__(256, 3) void gemm_kernel(
    const unsigned short* __restrict__ Xb, const unsigned short* __restrict__ Wb,
    const float* __restrict__ xscale, const float* __restrict__ bias,
    const float* __restrict__ gate, float* __restrict__ out) {
    __shared__ unsigned short lds[2 * 128 * 64];   // A: [0,8192), B: [8192,16384) ushorts

    const int tid  = threadIdx.x;
    const int lane = tid & 63;
    const int wave = tid >> 6;
    const long row0 = (long)blockIdx.y * 128;   // m
    const long col0 = (long)blockIdx.x * 128;   // n

    // staging addressing: slot s = i*256 + tid ; row = s/8 ; chunkslot = tid&7
    const int srow   = tid >> 3;                       // 0..31 (+ i*32)
    const int gchunk = (tid & 7) ^ (srow & 7);         // XOR swizzle source chunk
    const unsigned short* gA = Xb + (row0 + srow) * KDIM + gchunk * 8;
    const unsigned short* gB = Wb + (col0 + srow) * KDIM + gchunk * 8;
    unsigned short* lA = lds + wave * 512;             // +i*2048 per issue
    unsigned short* lB = lds + 8192 + wave * 512;

    const int wm   = (wave >> 1) * 64;
    const int wn   = (wave & 1) * 64;
    const int fr   = lane & 15;
    const int quad = lane >> 4;
    const int sw   = lane & 7;   // row&7 of every fragment row this lane touches

    floatx4 acc[4][4] = {};

    for (long kk = 0; kk < KDIM; kk += 64) {
        __syncthreads();   // previous tile's ds_reads complete before overwrite
#pragma unroll
        for (int i = 0; i < 4; ++i) {
            __builtin_amdgcn_global_load_lds(
                (const __attribute__((address_space(1))) void*)(gA + (long)i * 32 * KDIM + kk),
                (__attribute__((address_space(3))) void*)(lA + i * 2048), 16, 0, 0);
            __builtin_amdgcn_global_load_lds(
                (const __attribute__((address_space(1))) void*)(gB + (long)i * 32 * KDIM + kk),
                (__attribute__((address_space(3))) void*)(lB + i * 2048), 16, 0, 0);
        }
        __syncthreads();   // compiler drains vmcnt(0) before s_barrier

#pragma unroll
        for (int s = 0; s < 2; ++s) {   // two k=32 steps per BK=64 tile
            bf16x8 af[4], bfr[4];
#pragma unroll
            for (int t = 0; t < 4; ++t) {
                const int ca = ((s * 4 + quad) ^ sw) * 8;   // swizzled chunk -> elem offset
                af[t]  = *reinterpret_cast<const bf16x8*>(lds + (wm + t * 16 + fr) * 64 + ca);
                bfr[t] = *reinterpret_cast<const bf16x8*>(lds + 8192 + (wn + t * 16 + fr) * 64 + ca);
            }
#pragma unroll
            for (int i = 0; i < 4; ++i)
#pragma unroll
                for (int j = 0; j < 4; ++j)
                    acc[i][j] = __builtin_amdgcn_mfma_f32_16x16x32_bf16(
                        af[i], bfr[j], acc[i][j], 0, 0, 0);
        }
    }

    // Epilogue: D row = quad*4 + reg, col = lane&15 (m89-verified layout)
#pragma unroll
    for (int i = 0; i < 4; ++i) {
#pragma unroll
        for (int r = 0; r < 4; ++r) {
            const long gm = row0 + wm + i * 16 + quad * 4 + r;
            const float sc = xscale[gm];
            const long rowoff = gm * NDIM;
#pragma unroll
            for (int j = 0; j < 4; ++j) {
                const long gn = col0 + wn + j * 16 + fr;
                float v = acc[i][j][r] * sc + bias[gn];
                out[rowoff + gn] = v * gate[rowoff + gn];
            }
        }
    }
}

extern "C" void kernel_launch(void* const* d_in, const int* in_sizes, int n_in,
                              void* d_out, int out_size, void* d_ws, size_t ws_size,
                              hipStream_t stream) {
    const float* x       = (const float*)d_in[0];   // [M,K] fp32
    const float* xscale  = (const float*)d_in[1];   // [M]
    const int*   wq      = (const int*)d_in[2];     // [N,K/8]
    const float* wscale  = (const float*)d_in[3];   // [N,K/GS]
    const float* gate    = (const float*)d_in[4];   // [M,N]
    const float* bias    = (const float*)d_in[5];   // [N]
    float* out = (float*)d_out;

    // workspace layout: x_bf16 [M*K] ushort, then w_bf16 [N*K] ushort
    unsigned short* xb = (unsigned short*)d_ws;                    // 67,108,864 B
    unsigned short* wb = (unsigned short*)((char*)d_ws + (size_t)MDIM * KDIM * 2);

    convert_x_kernel<<<dim3((int)(MDIM * KDIM / 8 / 256)), dim3(256), 0, stream>>>(x, xb);
    dequant_w_kernel<<<dim3((int)(NDIM * KDIM / 8 / 256)), dim3(256), 0, stream>>>(wq, wscale, wb);

    dim3 grid((int)(NDIM / 128), (int)(MDIM / 128));   // 112 x 64
    gemm_kernel<<<grid, dim3(256), 0, stream>>>(xb, wb, xscale, bias, gate, out);
}